// Round 10
// baseline (277.010 us; speedup 1.0000x reference)
//
#include <hip/hip_runtime.h>

#define LL 2048
#define NN 4
#define EE 768
#define HH 12
#define RR 16
#define HD 64
#define TT (LL*NN)    // 8192 tokens
#define F3 (3*EE)     // 2304

typedef __bf16 bf16;
typedef bf16 bf16x4 __attribute__((ext_vector_type(4)));
typedef bf16 bf16x8 __attribute__((ext_vector_type(8)));
typedef float floatx4 __attribute__((ext_vector_type(4)));
typedef float floatx16 __attribute__((ext_vector_type(16)));
typedef unsigned uintx4 __attribute__((ext_vector_type(4)));

#define ZERO16 (floatx16){0.f,0.f,0.f,0.f,0.f,0.f,0.f,0.f,0.f,0.f,0.f,0.f,0.f,0.f,0.f,0.f}

__device__ __forceinline__ unsigned pk_bf16(float a, float b) {
    unsigned r;
    asm("v_cvt_pk_bf16_f32 %0, %1, %2" : "=v"(r) : "v"(a), "v"(b));
    return r;
}

// ---------------------------------------------------------------------------
// prep_w: fold LoRA into the base weights:
//   W_eff[f][e] = W[f][e] + sum_r up[f][r] * down[r][e]   (LORA_SCALE = 1)
// Wa bf16 [3072][EE]: rows 0..2303 = q/k/v in-proj, 2304..3071 = out-proj.
// ---------------------------------------------------------------------------
__global__ __launch_bounds__(256) void prep_w(
    const float* __restrict__ W,  const float* __restrict__ qu,
    const float* __restrict__ ku, const float* __restrict__ vu,
    const float* __restrict__ Wo, const float* __restrict__ ou,
    const float* __restrict__ qd, const float* __restrict__ kd,
    const float* __restrict__ vd, const float* __restrict__ odw,
    bf16* __restrict__ Wa)
{
    const int f0 = blockIdx.x * 16;       // 0..3056, step 16 (within one third)
    const int tid = threadIdx.x;

    const float* Wsrc;
    const float* up;
    const float* dn;
    if (f0 < F3) {
        const int third = f0 / EE, fe = f0 % EE;
        Wsrc = W + (size_t)f0*EE;
        up   = ((third == 0) ? qu : (third == 1) ? ku : vu) + (size_t)fe*RR;
        dn   = (third == 0) ? qd : (third == 1) ? kd : vd;
    } else {
        const int fe = f0 - F3;
        Wsrc = Wo + (size_t)fe*EE;
        up   = ou + (size_t)fe*RR;
        dn   = odw;
    }

    // cache down[r][e] for this thread's 3 columns
    float dnv[3][RR];
    #pragma unroll
    for (int i = 0; i < 3; ++i)
        #pragma unroll
        for (int r = 0; r < RR; ++r)
            dnv[i][r] = dn[(size_t)r*EE + i*256 + tid];

    for (int fr = 0; fr < 16; ++fr) {
        float u[RR];
        #pragma unroll
        for (int r = 0; r < RR; ++r) u[r] = up[(size_t)fr*RR + r];
        bf16* orow = Wa + (size_t)(f0 + fr)*EE;
        #pragma unroll
        for (int i = 0; i < 3; ++i) {
            float acc = Wsrc[(size_t)fr*EE + i*256 + tid];
            #pragma unroll
            for (int r = 0; r < RR; ++r) acc += u[r] * dnv[i][r];
            orow[i*256 + tid] = (bf16)acc;
        }
    }
}

// ---------------------------------------------------------------------------
// gemm_aug: C[t][f] = sum_k A[t][k]*B[f][k] + bias[f]  over K=EE=768.
// attn-style 1-barrier double-buffered schedule: per tile
//   { STORE next-tile regs -> other LDS buf; issue LOADT(tile+2);
//     compute(cur buf); barrier }
// so the STORE's vmcnt waits on loads a FULL iteration old (slack >> HBM
// latency) and there is one barrier per k-tile.  LDS unpadded [128][64]x4
// = 64 KB (2 blocks/CU), bank conflicts handled by the XOR swizzle verified
// in attn (write side cg^row&7) and round-7 gemm (read side (kc*4+quad)^swr).
// MODE 0: A = fp32 q/k/v (cast fused via v_cvt_pk_bf16_f32, bit-identical
//         to a separate cast pass); outputs bf16 (nh,l,d), q scaled
//         0.125*log2e.   MODE 1: A = bf16 Oa; fp32 out.
// ---------------------------------------------------------------------------
template<int MODE>
__global__ __launch_bounds__(256, 2) void gemm_aug(
    const float* __restrict__ Aq, const float* __restrict__ Ak,
    const float* __restrict__ Av, const bf16* __restrict__ Abf,
    const bf16* __restrict__ B,
    const float* __restrict__ bias,
    bf16* __restrict__ qo, bf16* __restrict__ ko, bf16* __restrict__ vo,
    float* __restrict__ fo)
{
    __shared__ bf16 AsA[128][64], BsA[128][64];   // buffer A, 32 KB
    __shared__ bf16 AsB[128][64], BsB[128][64];   // buffer B, 32 KB
    const int t0 = blockIdx.x * 128;
    const int f0 = blockIdx.y * 128;
    const int tid = threadIdx.x;
    const int wave = tid >> 6, lane = tid & 63;
    const int quad = lane >> 4, l16 = lane & 15;
    const int m0 = (wave & 1) * 64;
    const int n0 = (wave >> 1) * 64;
    const int swr = l16 & 7;                      // read-side swizzle

    const int third = (MODE == 0) ? (f0 / EE) : 0;
    const float* A32 = (MODE == 0)
        ? ((third == 0) ? Aq : (third == 1) ? Ak : Av) : nullptr;

    // staging geometry: chunk c -> row c*32 + r0, logical 16B group cg,
    // physical LDS group gsw = cg ^ (row&7)   (row&7 == r0&7, c*32 = 0 mod 8)
    const int r0 = tid >> 3, cg = tid & 7;
    const int gsw = cg ^ (r0 & 7);

    // staging registers (one k-tile in flight)
    float4 ga0[4], ga1[4];      // MODE 0: fp32 A
    bf16x8 gab[4];              // MODE 1: bf16 A
    bf16x8 gbb[4];              // B

#define LOADT(kb) do {                                                        \
        _Pragma("unroll")                                                     \
        for (int c = 0; c < 4; ++c) {                                         \
            if constexpr (MODE == 0) {                                        \
                const float* src =                                            \
                    A32 + (size_t)(t0 + c*32 + r0)*EE + (kb)*64 + cg*8;       \
                ga0[c] = *(const float4*)(src);                               \
                ga1[c] = *(const float4*)(src + 4);                           \
            } else {                                                          \
                gab[c] = *(const bf16x8*)(                                    \
                    Abf + (size_t)(t0 + c*32 + r0)*EE + (kb)*64 + cg*8);      \
            }                                                                 \
            gbb[c] = *(const bf16x8*)(                                        \
                B + (size_t)(f0 + c*32 + r0)*EE + (kb)*64 + cg*8);            \
        }                                                                     \
    } while (0)
#define STORET(AS, BS) do {                                                   \
        _Pragma("unroll")                                                     \
        for (int c = 0; c < 4; ++c) {                                         \
            if constexpr (MODE == 0) {                                        \
                union { uintx4 u; bf16x8 h; } cv;                             \
                cv.u = (uintx4){ pk_bf16(ga0[c].x, ga0[c].y),                 \
                                 pk_bf16(ga0[c].z, ga0[c].w),                 \
                                 pk_bf16(ga1[c].x, ga1[c].y),                 \
                                 pk_bf16(ga1[c].z, ga1[c].w) };               \
                *(bf16x8*)(&AS[c*32 + r0][gsw*8]) = cv.h;                     \
            } else {                                                          \
                *(bf16x8*)(&AS[c*32 + r0][gsw*8]) = gab[c];                   \
            }                                                                 \
            *(bf16x8*)(&BS[c*32 + r0][gsw*8]) = gbb[c];                       \
        }                                                                     \
    } while (0)
#define COMPUTE(AS, BS) do {                                                  \
        _Pragma("unroll")                                                     \
        for (int kc = 0; kc < 2; ++kc) {                                      \
            bf16x8 a[4], bfr[4];                                              \
            _Pragma("unroll")                                                 \
            for (int rt = 0; rt < 4; ++rt)                                    \
                a[rt] = *(const bf16x8*)(                                     \
                    &AS[m0 + rt*16 + l16][((kc*4 + quad) ^ swr) * 8]);        \
            _Pragma("unroll")                                                 \
            for (int ct = 0; ct < 4; ++ct)                                    \
                bfr[ct] = *(const bf16x8*)(                                   \
                    &BS[n0 + ct*16 + l16][((kc*4 + quad) ^ swr) * 8]);        \
            _Pragma("unroll")                                                 \
            for (int rt = 0; rt < 4; ++rt)                                    \
                _Pragma("unroll")                                             \
                for (int ct = 0; ct < 4; ++ct)                                \
                    acc[rt][ct] = __builtin_amdgcn_mfma_f32_16x16x32_bf16(    \
                        a[rt], bfr[ct], acc[rt][ct], 0, 0, 0);                \
        }                                                                     \
    } while (0)

    floatx4 acc[4][4];
    #pragma unroll
    for (int rt = 0; rt < 4; ++rt)
        #pragma unroll
        for (int ct = 0; ct < 4; ++ct) acc[rt][ct] = (floatx4){0.f,0.f,0.f,0.f};

    const int NT = EE/64;                    // 12 k-tiles
    LOADT(0);
    STORET(AsA, BsA);                        // tile 0 -> A
    LOADT(1);                                // tile 1 in regs
    __syncthreads();

    for (int tt = 0; tt < NT/2; ++tt) {
        STORET(AsB, BsB);                    // tile 2tt+1 -> B
        { int k2 = 2*tt + 2; if (k2 >= NT) k2 -= NT; LOADT(k2); }
        COMPUTE(AsA, BsA);                   // tile 2tt
        __syncthreads();                     // B visible; all reads of A done
        STORET(AsA, BsA);                    // tile 2tt+2 -> A (wraps at end)
        { int k3 = 2*tt + 3; if (k3 >= NT) k3 -= NT; LOADT(k3); }
        COMPUTE(AsB, BsB);                   // tile 2tt+1
        __syncthreads();                     // A visible; all reads of B done
    }
#undef LOADT
#undef STORET
#undef COMPUTE

    #pragma unroll
    for (int rt = 0; rt < 4; ++rt) {
        #pragma unroll
        for (int r = 0; r < 4; ++r) {
            const int t = t0 + m0 + rt*16 + quad*4 + r;
            #pragma unroll
            for (int ct = 0; ct < 4; ++ct) {
                const int fl = n0 + ct*16 + l16;
                float c = acc[rt][ct][r] + bias[f0 + fl];
                if (MODE == 0) {
                    const int fe = (f0 % EE) + fl;
                    const int h = fe >> 6, d = fe & 63;
                    const int l = t >> 2, n = t & 3;
                    const size_t idx = (((size_t)(n*HH + h)*LL) + l)*HD + d;
                    // q: fold 1/sqrt(64) and log2(e) so softmax uses exp2
                    if (third == 0)      qo[idx] = (bf16)(c * 0.180336877f);
                    else if (third == 1) ko[idx] = (bf16)c;
                    else                 vo[idx] = (bf16)c;
                } else {
                    fo[(size_t)t*EE + f0 + fl] = c;
                }
            }
        }
    }
}

// ---------------------------------------------------------------------------
// vtrans: vld (nh,l,d) bf16 -> vfb (nh,d,l) bf16, 64x64 LDS tiles (xor-swizzled)
// ---------------------------------------------------------------------------
__global__ __launch_bounds__(256) void vtrans(
    const bf16* __restrict__ vin, bf16* __restrict__ vout)
{
    __shared__ bf16 T[64][64];
    const int nh = blockIdx.x >> 5;
    const int l0 = (blockIdx.x & 31) * 64;
    const int tid = threadIdx.x;
    const bf16* src = vin + ((size_t)nh*LL + l0)*HD;
    #pragma unroll
    for (int c = 0; c < 2; ++c) {
        int id = c*256 + tid;
        int row = id >> 3, dg = id & 7;
        int pg = dg ^ (row & 7);
        *(bf16x8*)(&T[row][pg*8]) = *(const bf16x8*)(src + row*HD + dg*8);
    }
    __syncthreads();
    bf16* dst = vout + (size_t)nh*HD*LL;
    const int wave = tid >> 6, lane = tid & 63;
    #pragma unroll
    for (int it = 0; it < 2; ++it) {
        const int d  = it*32 + wave*8 + (lane >> 3);
        const int cg = lane & 7;
        bf16x8 vv;
        #pragma unroll
        for (int j = 0; j < 8; ++j) {
            const int lrow = cg*8 + j;
            const int pg = (d >> 3) ^ (lrow & 7);
            vv[j] = T[lrow][pg*8 + (d & 7)];
        }
        *(bf16x8*)(dst + (size_t)d*LL + l0 + cg*8) = vv;
    }
}

// ---------------------------------------------------------------------------
// attn_mfma: block = 128 queries of one (n,h); 4 waves x 32 query rows.
// Round-6 verified structure, unchanged (reg-staged A/B LDS tiles,
// XOR-swizzled, swapped QK^T + in-register softmax via raw v_exp_f32,
// ones-MFMA row sums, setprio around MFMA clusters).
// Fixed-max softmax (scores bounded; softmax shift-invariant -> exact).
// ---------------------------------------------------------------------------
__device__ __forceinline__ void compute_tile(
    const bf16 (&KS)[64][64], const bf16 (&VS)[64][64],
    const bf16x8 (&bq)[4], const bf16x8& ones, const floatx16& z16,
    int l32, int hi, int sw,
    floatx16& oacc0, floatx16& oacc1, floatx16& oaccS)
{
    #pragma unroll
    for (int ss = 0; ss < 2; ++ss) {
        // K A-fragments: row = s_loc = ss*32 + l32, k = t4*16 + hi*8 + j
        bf16x8 ak[4];
        #pragma unroll
        for (int t4 = 0; t4 < 4; ++t4)
            ak[t4] = *(const bf16x8*)(&KS[ss*32 + l32][((t4*2 + hi) ^ sw) * 8]);

        __builtin_amdgcn_s_setprio(1);
        floatx16 sacc = __builtin_amdgcn_mfma_f32_32x32x16_bf16(
            ak[0], bq[0], z16, 0, 0, 0);
        #pragma unroll
        for (int t4 = 1; t4 < 4; ++t4)
            sacc = __builtin_amdgcn_mfma_f32_32x32x16_bf16(
                ak[t4], bq[t4], sacc, 0, 0, 0);
        __builtin_amdgcn_s_setprio(0);

        // V B-fragments: bv[tl*2+dt][j] = V^T[dt*32+l32][ss*32+tl*16+hi*8+j]
        bf16x8 bv[4];
        #pragma unroll
        for (int tl = 0; tl < 2; ++tl)
            #pragma unroll
            for (int dt = 0; dt < 2; ++dt)
                bv[tl*2 + dt] = *(const bf16x8*)(
                    &VS[dt*32 + l32][((ss*4 + tl*2 + hi) ^ sw) * 8]);

        // softmax numerator, lane-local: p[r] = P[q=l32][crow(r,hi)]
        // raw v_exp_f32 (exact here: scores bounded, log2e pre-folded)
        float p[16];
        #pragma unroll
        for (int r = 0; r < 16; ++r) p[r] = __builtin_amdgcn_exp2f(sacc[r]);

        // pack to PV A-fragments: fr0 -> s_loc 0..15, fr1 -> s_loc 16..31
        union { uintx4 u; bf16x8 h; } fr0, fr1;
        {
            unsigned c0 = pk_bf16(p[0], p[1]);
            unsigned c1 = pk_bf16(p[2], p[3]);
            unsigned c2 = pk_bf16(p[4], p[5]);
            unsigned c3 = pk_bf16(p[6], p[7]);
            asm("v_permlane32_swap_b32 %0, %1" : "+v"(c0), "+v"(c2));
            asm("v_permlane32_swap_b32 %0, %1" : "+v"(c1), "+v"(c3));
            fr0.u = (uintx4){c0, c1, c2, c3};
        }
        {
            unsigned c0 = pk_bf16(p[8],  p[9]);
            unsigned c1 = pk_bf16(p[10], p[11]);
            unsigned c2 = pk_bf16(p[12], p[13]);
            unsigned c3 = pk_bf16(p[14], p[15]);
            asm("v_permlane32_swap_b32 %0, %1" : "+v"(c0), "+v"(c2));
            asm("v_permlane32_swap_b32 %0, %1" : "+v"(c1), "+v"(c3));
            fr1.u = (uintx4){c0, c1, c2, c3};
        }

        // denominator via ones-MFMA: oaccS row q = sum_s P[q][s] (all cols)
        __builtin_amdgcn_s_setprio(1);
        oaccS = __builtin_amdgcn_mfma_f32_32x32x16_bf16(fr0.h, ones, oaccS, 0, 0, 0);
        oaccS = __builtin_amdgcn_mfma_f32_32x32x16_bf16(fr1.h, ones, oaccS, 0, 0, 0);
        // PV: O[q][d] += P[q][s_loc] * V[s+s_loc][d]
        oacc0 = __builtin_amdgcn_mfma_f32_32x32x16_bf16(fr0.h, bv[0], oacc0, 0, 0, 0);
        oacc1 = __builtin_amdgcn_mfma_f32_32x32x16_bf16(fr0.h, bv[1], oacc1, 0, 0, 0);
        oacc0 = __builtin_amdgcn_mfma_f32_32x32x16_bf16(fr1.h, bv[2], oacc0, 0, 0, 0);
        oacc1 = __builtin_amdgcn_mfma_f32_32x32x16_bf16(fr1.h, bv[3], oacc1, 0, 0, 0);
        __builtin_amdgcn_s_setprio(0);
    }
}

__global__ __launch_bounds__(256, 3) void attn_mfma(
    const bf16* __restrict__ qf, const bf16* __restrict__ kf,
    const bf16* __restrict__ vf, bf16* __restrict__ Oa)
{
    __shared__ bf16 KsA[64][64], VtA[64][64];   // 16 KB (buffer A)
    __shared__ bf16 KsB[64][64], VtB[64][64];   // 16 KB (buffer B)

    const int bid = blockIdx.x;
    const int nh = bid % 48;                 // same head -> same XCD (bid%8 const)
    const int l0 = (bid / 48) * 128;
    const int tid  = threadIdx.x;
    const int wave = tid >> 6;
    const int lane = tid & 63;
    const int l32  = lane & 31;
    const int hi   = lane >> 5;
    const int sw   = l32 & 7;                // read-side swizzle

    const bf16* qb = qf + (size_t)nh * LL * HD;
    const bf16* kb = kf + (size_t)nh * LL * HD;
    const bf16* vb = vf + (size_t)nh * HD * LL;

    const int q0 = l0 + wave * 32;

    // staging geometry: 64 rows x 8 slots (16B) per tile; 2 chunks/thread
    const int rowA = tid >> 3;               // 0..31
    const int rowB = rowA + 32;              // 32..63
    const int g0   = tid & 7;                // logical slot
    const int gsA  = g0 ^ (rowA & 7);        // physical slot (rowB&7 == rowA&7)

    const bf16* pK0 = kb + (size_t)rowA*HD + g0*8;
    const bf16* pK1 = kb + (size_t)rowB*HD + g0*8;
    const bf16* pV0 = vb + (size_t)rowA*LL + g0*8;
    const bf16* pV1 = vb + (size_t)rowB*LL + g0*8;

    // Q B-fragments (col = q = l32, k-slice t): Q[q0+l32][t*16 + hi*8 + j]
    bf16x8 bq[4];
    #pragma unroll
    for (int t = 0; t < 4; ++t)
        bq[t] = *(const bf16x8*)(qb + (size_t)(q0 + l32)*HD + t*16 + hi*8);

    const bf16x8 ones = { (bf16)1.f, (bf16)1.f, (bf16)1.f, (bf16)1.f,
                          (bf16)1.f, (bf16)1.f, (bf16)1.f, (bf16)1.f };
    const floatx16 z16 = ZERO16;

    floatx16 oacc0 = ZERO16;   // O[q][d=l32]
    floatx16 oacc1 = ZERO16;   // O[q][d=32+l32]
    floatx16 oaccS = ZERO16;   // row sums (denominator)

    bf16x8 gk0, gk1, gv0, gv1;               // reg-staged tile

#define LOADT(S) do {                                                         \
        gk0 = *(const bf16x8*)(pK0 + (size_t)(S)*HD);                         \
        gk1 = *(const bf16x8*)(pK1 + (size_t)(S)*HD);                         \
        gv0 = *(const bf16x8*)(pV0 + (S));                                    \
        gv1 = *(const bf16x8*)(pV1 + (S));                                    \
    } while (0)
#define STORE_A() do {                                                        \
        *(bf16x8*)(&KsA[rowA][gsA*8]) = gk0;                                  \
        *(bf16x8*)(&KsA[rowB][gsA*8]) = gk1;                                  \
        *(bf16x8*)(&VtA[rowA][gsA*8]) = gv0;                                  \
        *(bf16x8*)(&VtA[rowB][gsA*8]) = gv1;                                  \
    } while (0)
#define STORE_B() do {                                                        \
        *(bf16x8*)(&KsB[rowA][gsA*8]) = gk0;                                  \
        *(bf16x8*)(&KsB[rowB][gsA*8]) = gk1;                                  \
        *(bf16x8*)(&VtB[rowA][gsA*8]) = gv0;                                  \
        *(bf16x8*)(&VtB[rowB][gsA*8]) = gv1;                                  \
    } while (0)

    LOADT(0);
    STORE_A();                               // tile 0 -> A
    LOADT(64);                               // tile 1 in regs
    __syncthreads();

    for (int tt = 0; tt < 16; ++tt) {
        STORE_B();                           // tile 2tt+1 -> B
        LOADT((size_t)((2*tt + 2) & 31) * 64);   // tile 2tt+2 (wraps at end)
        compute_tile(KsA, VtA, bq, ones, z16, l32, hi, sw, oacc0, oacc1, oaccS);
        __syncthreads();                     // B visible; all done reading A
        STORE_A();                           // tile 2tt+2 -> A
        LOADT((size_t)((2*tt + 3) & 31) * 64);   // tile 2tt+3 (wraps at end)
        compute_tile(KsB, VtB, bq, ones, z16, l32, hi, sw, oacc0, oacc1, oaccS);
        __syncthreads();                     // A visible; all done reading B
    }
#undef LOADT
#undef STORE_A
#undef STORE_B

    const int n = nh / HH, h = nh % HH;
    #pragma unroll
    for (int r = 0; r < 16; ++r) {
        const int qloc = (r & 3) + 8*(r >> 2) + 4*hi;
        const float iv = 1.f / oaccS[r];
        const size_t t = (size_t)(q0 + qloc)*NN + n;
        Oa[t*EE + h*64 + l32]      = (bf16)(oacc0[r] * iv);
        Oa[t*EE + h*64 + 32 + l32] = (bf16)(oacc1[r] * iv);
    }
}

// ---------------------------------------------------------------------------
extern "C" void kernel_launch(void* const* d_in, const int* in_sizes, int n_in,
                              void* d_out, int out_size, void* d_ws, size_t ws_size,
                              hipStream_t stream) {
    const float* q   = (const float*)d_in[0];
    const float* k   = (const float*)d_in[1];
    const float* v   = (const float*)d_in[2];
    const float* W   = (const float*)d_in[3];
    const float* b   = (const float*)d_in[4];
    const float* qd  = (const float*)d_in[5];
    const float* qu  = (const float*)d_in[6];
    const float* kd  = (const float*)d_in[7];
    const float* ku  = (const float*)d_in[8];
    const float* vd  = (const float*)d_in[9];
    const float* vu  = (const float*)d_in[10];
    const float* Wo  = (const float*)d_in[11];
    const float* bo  = (const float*)d_in[12];
    const float* odw = (const float*)d_in[13];
    const float* ou  = (const float*)d_in[14];
    float* out = (float*)d_out;

    char* wsb = (char*)d_ws;
    bf16* vfb = (bf16*)wsb;                       // [48][HD][LL]
    bf16* Oa  = (bf16*)(wsb + (size_t)TT*EE*2);   // [TT][EE]
    bf16* Wa  = (bf16*)(wsb + (size_t)3*TT*EE*2); // [3072][EE], 4.72 MB
    bf16* qfb = Wa + (size_t)3072*EE;
    bf16* kfb = qfb + (size_t)TT*EE;
    bf16* vld = kfb + (size_t)TT*EE;

    prep_w<<<192, 256, 0, stream>>>(W, qu, ku, vu, Wo, ou, qd, kd, vd, odw, Wa);
    gemm_aug<0><<<dim3(TT/128, F3/128), 256, 0, stream>>>(
        q, k, v, nullptr, Wa, b, qfb, kfb, vld, nullptr);
    vtrans<<<48*32, 256, 0, stream>>>(vld, vfb);
    attn_mfma<<<48*16, 256, 0, stream>>>(qfb, kfb, vfb, Oa);
    gemm_aug<1><<<dim3(TT/128, EE/128), 256, 0, stream>>>(
        nullptr, nullptr, nullptr, Oa, Wa + (size_t)F3*EE, bo,
        nullptr, nullptr, nullptr, out);
}

// Round 11
// 274.681 us; speedup vs baseline: 1.0085x; 1.0085x over previous
//
#include <hip/hip_runtime.h>

#define LL 2048
#define NN 4
#define EE 768
#define HH 12
#define RR 16
#define HD 64
#define TT (LL*NN)    // 8192 tokens
#define F3 (3*EE)     // 2304

typedef __bf16 bf16;
typedef bf16 bf16x4 __attribute__((ext_vector_type(4)));
typedef bf16 bf16x8 __attribute__((ext_vector_type(8)));
typedef float floatx4 __attribute__((ext_vector_type(4)));
typedef float floatx16 __attribute__((ext_vector_type(16)));
typedef unsigned uintx4 __attribute__((ext_vector_type(4)));

#define ZERO16 (floatx16){0.f,0.f,0.f,0.f,0.f,0.f,0.f,0.f,0.f,0.f,0.f,0.f,0.f,0.f,0.f,0.f}

__device__ __forceinline__ unsigned pk_bf16(float a, float b) {
    unsigned r;
    asm("v_cvt_pk_bf16_f32 %0, %1, %2" : "=v"(r) : "v"(a), "v"(b));
    return r;
}

// ---------------------------------------------------------------------------
// prep_w: fold LoRA into the base weights:
//   W_eff[f][e] = W[f][e] + sum_r up[f][r] * down[r][e]   (LORA_SCALE = 1)
// Wa bf16 [3072][EE]: rows 0..2303 = q/k/v in-proj, 2304..3071 = out-proj.
// ---------------------------------------------------------------------------
__global__ __launch_bounds__(256) void prep_w(
    const float* __restrict__ W,  const float* __restrict__ qu,
    const float* __restrict__ ku, const float* __restrict__ vu,
    const float* __restrict__ Wo, const float* __restrict__ ou,
    const float* __restrict__ qd, const float* __restrict__ kd,
    const float* __restrict__ vd, const float* __restrict__ odw,
    bf16* __restrict__ Wa)
{
    const int f0 = blockIdx.x * 16;       // 0..3056, step 16 (within one third)
    const int tid = threadIdx.x;

    const float* Wsrc;
    const float* up;
    const float* dn;
    if (f0 < F3) {
        const int third = f0 / EE, fe = f0 % EE;
        Wsrc = W + (size_t)f0*EE;
        up   = ((third == 0) ? qu : (third == 1) ? ku : vu) + (size_t)fe*RR;
        dn   = (third == 0) ? qd : (third == 1) ? kd : vd;
    } else {
        const int fe = f0 - F3;
        Wsrc = Wo + (size_t)fe*EE;
        up   = ou + (size_t)fe*RR;
        dn   = odw;
    }

    // cache down[r][e] for this thread's 3 columns
    float dnv[3][RR];
    #pragma unroll
    for (int i = 0; i < 3; ++i)
        #pragma unroll
        for (int r = 0; r < RR; ++r)
            dnv[i][r] = dn[(size_t)r*EE + i*256 + tid];

    for (int fr = 0; fr < 16; ++fr) {
        float u[RR];
        #pragma unroll
        for (int r = 0; r < RR; ++r) u[r] = up[(size_t)fr*RR + r];
        bf16* orow = Wa + (size_t)(f0 + fr)*EE;
        #pragma unroll
        for (int i = 0; i < 3; ++i) {
            float acc = Wsrc[(size_t)fr*EE + i*256 + tid];
            #pragma unroll
            for (int r = 0; r < RR; ++r) acc += u[r] * dnv[i][r];
            orow[i*256 + tid] = (bf16)acc;
        }
    }
}

// ---------------------------------------------------------------------------
// gemm_aug: C[t][f] = sum_k A[t][k]*B[f][k] + bias[f]  over K=EE=768.
// BK=128 (6 k-tiles): half the barrier events of BK=64; 64 MFMA (~640 cyc)
// between barriers fully covers the prefetched loads' HBM latency.
// Single-buffered [128][128] LDS x2 = 64 KB (2 blocks/CU -- round-10 showed
// 2 vs 3 blocks is perf-neutral here).  16-chunk XOR swizzle:
//   write phys chunk = (tid&15) ^ (tid>>4)  (lane-constant)
//   read  phys chunk = (kc*4+quad) ^ l16
// -> 2-way bank aliasing both sides (free, m136).
// Schedule per tile: { COMPUTE(cur); bar; STORET(next); LOADT(next+1); bar }
// so every vmcnt wait has a full compute phase of slack.
// MODE 0: A = fp32 q/k/v (cast fused via v_cvt_pk_bf16_f32); outputs bf16
//         (nh,l,d), q scaled 0.125*log2e.   MODE 1: A = bf16 Oa; fp32 out.
// ---------------------------------------------------------------------------
template<int MODE>
__global__ __launch_bounds__(256, 2) void gemm_aug(
    const float* __restrict__ Aq, const float* __restrict__ Ak,
    const float* __restrict__ Av, const bf16* __restrict__ Abf,
    const bf16* __restrict__ B,
    const float* __restrict__ bias,
    bf16* __restrict__ qo, bf16* __restrict__ ko, bf16* __restrict__ vo,
    float* __restrict__ fo)
{
    __shared__ bf16 As[128][128];        // 32 KB
    __shared__ bf16 Bs[128][128];        // 32 KB
    const int t0 = blockIdx.x * 128;
    const int f0 = blockIdx.y * 128;
    const int tid = threadIdx.x;
    const int wave = tid >> 6, lane = tid & 63;
    const int quad = lane >> 4, l16 = lane & 15;
    const int m0 = (wave & 1) * 64;
    const int n0 = (wave >> 1) * 64;

    const int third = (MODE == 0) ? (f0 / EE) : 0;
    const float* A32 = (MODE == 0)
        ? ((third == 0) ? Aq : (third == 1) ? Ak : Av) : nullptr;

    // staging geometry: 128 rows x 16 chunks(16B); thread -> 8 chunks:
    // rows c*16 + sr (c=0..7), chunk col sc; physical col scp = sc ^ sr
    const int sr = tid >> 4;             // 0..15
    const int sc = tid & 15;             // 0..15
    const int scp = sc ^ sr;             // write-side swizzle (lane-constant)

    // staging registers (one BK=128 k-tile in flight)
    float4 ga[16];              // MODE 0: fp32 A (8 chunks x 2 float4)
    bf16x8 gab[8];              // MODE 1: bf16 A
    bf16x8 gbb[8];              // B

#define LOADT(kb) do {                                                        \
        _Pragma("unroll")                                                     \
        for (int c = 0; c < 8; ++c) {                                         \
            const int row = c*16 + sr;                                        \
            if constexpr (MODE == 0) {                                        \
                const float* src =                                            \
                    A32 + (size_t)(t0 + row)*EE + (kb)*128 + sc*8;            \
                ga[2*c]   = *(const float4*)(src);                            \
                ga[2*c+1] = *(const float4*)(src + 4);                        \
            } else {                                                          \
                gab[c] = *(const bf16x8*)(                                    \
                    Abf + (size_t)(t0 + row)*EE + (kb)*128 + sc*8);           \
            }                                                                 \
            gbb[c] = *(const bf16x8*)(                                        \
                B + (size_t)(f0 + row)*EE + (kb)*128 + sc*8);                 \
        }                                                                     \
    } while (0)
#define STORET() do {                                                         \
        _Pragma("unroll")                                                     \
        for (int c = 0; c < 8; ++c) {                                         \
            const int row = c*16 + sr;                                        \
            if constexpr (MODE == 0) {                                        \
                union { uintx4 u; bf16x8 h; } cv;                             \
                cv.u = (uintx4){ pk_bf16(ga[2*c].x,   ga[2*c].y),             \
                                 pk_bf16(ga[2*c].z,   ga[2*c].w),             \
                                 pk_bf16(ga[2*c+1].x, ga[2*c+1].y),           \
                                 pk_bf16(ga[2*c+1].z, ga[2*c+1].w) };         \
                *(bf16x8*)(&As[row][scp*8]) = cv.h;                           \
            } else {                                                          \
                *(bf16x8*)(&As[row][scp*8]) = gab[c];                         \
            }                                                                 \
            *(bf16x8*)(&Bs[row][scp*8]) = gbb[c];                             \
        }                                                                     \
    } while (0)
#define COMPUTE() do {                                                        \
        _Pragma("unroll")                                                     \
        for (int kc = 0; kc < 4; ++kc) {                                      \
            bf16x8 a[4], bfr[4];                                              \
            _Pragma("unroll")                                                 \
            for (int rt = 0; rt < 4; ++rt)                                    \
                a[rt] = *(const bf16x8*)(                                     \
                    &As[m0 + rt*16 + l16][((kc*4 + quad) ^ l16) * 8]);        \
            _Pragma("unroll")                                                 \
            for (int ct = 0; ct < 4; ++ct)                                    \
                bfr[ct] = *(const bf16x8*)(                                   \
                    &Bs[n0 + ct*16 + l16][((kc*4 + quad) ^ l16) * 8]);        \
            _Pragma("unroll")                                                 \
            for (int rt = 0; rt < 4; ++rt)                                    \
                _Pragma("unroll")                                             \
                for (int ct = 0; ct < 4; ++ct)                                \
                    acc[rt][ct] = __builtin_amdgcn_mfma_f32_16x16x32_bf16(    \
                        a[rt], bfr[ct], acc[rt][ct], 0, 0, 0);                \
        }                                                                     \
    } while (0)

    floatx4 acc[4][4];
    #pragma unroll
    for (int rt = 0; rt < 4; ++rt)
        #pragma unroll
        for (int ct = 0; ct < 4; ++ct) acc[rt][ct] = (floatx4){0.f,0.f,0.f,0.f};

    const int NT = EE/128;               // 6 k-tiles
    LOADT(0);
    STORET();                            // tile 0 -> LDS
    LOADT(1);                            // tile 1 in regs
    __syncthreads();

    for (int kb = 0; kb < NT; ++kb) {
        COMPUTE();                       // tile kb
        __syncthreads();                 // all reads of LDS done
        if (kb + 1 < NT) {
            STORET();                    // tile kb+1 (regs loaded a full
                                         //  compute-phase ago)
            if (kb + 2 < NT) LOADT(kb + 2);
            __syncthreads();             // tile kb+1 visible
        }
    }
#undef LOADT
#undef STORET
#undef COMPUTE

    #pragma unroll
    for (int rt = 0; rt < 4; ++rt) {
        #pragma unroll
        for (int r = 0; r < 4; ++r) {
            const int t = t0 + m0 + rt*16 + quad*4 + r;
            #pragma unroll
            for (int ct = 0; ct < 4; ++ct) {
                const int fl = n0 + ct*16 + l16;
                float c = acc[rt][ct][r] + bias[f0 + fl];
                if (MODE == 0) {
                    const int fe = (f0 % EE) + fl;
                    const int h = fe >> 6, d = fe & 63;
                    const int l = t >> 2, n = t & 3;
                    const size_t idx = (((size_t)(n*HH + h)*LL) + l)*HD + d;
                    // q: fold 1/sqrt(64) and log2(e) so softmax uses exp2
                    if (third == 0)      qo[idx] = (bf16)(c * 0.180336877f);
                    else if (third == 1) ko[idx] = (bf16)c;
                    else                 vo[idx] = (bf16)c;
                } else {
                    fo[(size_t)t*EE + f0 + fl] = c;
                }
            }
        }
    }
}

// ---------------------------------------------------------------------------
// vtrans: vld (nh,l,d) bf16 -> vfb (nh,d,l) bf16, 64x64 LDS tiles (xor-swizzled)
// ---------------------------------------------------------------------------
__global__ __launch_bounds__(256) void vtrans(
    const bf16* __restrict__ vin, bf16* __restrict__ vout)
{
    __shared__ bf16 T[64][64];
    const int nh = blockIdx.x >> 5;
    const int l0 = (blockIdx.x & 31) * 64;
    const int tid = threadIdx.x;
    const bf16* src = vin + ((size_t)nh*LL + l0)*HD;
    #pragma unroll
    for (int c = 0; c < 2; ++c) {
        int id = c*256 + tid;
        int row = id >> 3, dg = id & 7;
        int pg = dg ^ (row & 7);
        *(bf16x8*)(&T[row][pg*8]) = *(const bf16x8*)(src + row*HD + dg*8);
    }
    __syncthreads();
    bf16* dst = vout + (size_t)nh*HD*LL;
    const int wave = tid >> 6, lane = tid & 63;
    #pragma unroll
    for (int it = 0; it < 2; ++it) {
        const int d  = it*32 + wave*8 + (lane >> 3);
        const int cg = lane & 7;
        bf16x8 vv;
        #pragma unroll
        for (int j = 0; j < 8; ++j) {
            const int lrow = cg*8 + j;
            const int pg = (d >> 3) ^ (lrow & 7);
            vv[j] = T[lrow][pg*8 + (d & 7)];
        }
        *(bf16x8*)(dst + (size_t)d*LL + l0 + cg*8) = vv;
    }
}

// ---------------------------------------------------------------------------
// attn_mfma: block = 128 queries of one (n,h); 4 waves x 32 query rows.
// Round-6 verified structure, unchanged (reg-staged A/B LDS tiles,
// XOR-swizzled, swapped QK^T + in-register softmax via raw v_exp_f32,
// ones-MFMA row sums, setprio around MFMA clusters).
// Fixed-max softmax (scores bounded; softmax shift-invariant -> exact).
// ---------------------------------------------------------------------------
__device__ __forceinline__ void compute_tile(
    const bf16 (&KS)[64][64], const bf16 (&VS)[64][64],
    const bf16x8 (&bq)[4], const bf16x8& ones, const floatx16& z16,
    int l32, int hi, int sw,
    floatx16& oacc0, floatx16& oacc1, floatx16& oaccS)
{
    #pragma unroll
    for (int ss = 0; ss < 2; ++ss) {
        // K A-fragments: row = s_loc = ss*32 + l32, k = t4*16 + hi*8 + j
        bf16x8 ak[4];
        #pragma unroll
        for (int t4 = 0; t4 < 4; ++t4)
            ak[t4] = *(const bf16x8*)(&KS[ss*32 + l32][((t4*2 + hi) ^ sw) * 8]);

        __builtin_amdgcn_s_setprio(1);
        floatx16 sacc = __builtin_amdgcn_mfma_f32_32x32x16_bf16(
            ak[0], bq[0], z16, 0, 0, 0);
        #pragma unroll
        for (int t4 = 1; t4 < 4; ++t4)
            sacc = __builtin_amdgcn_mfma_f32_32x32x16_bf16(
                ak[t4], bq[t4], sacc, 0, 0, 0);
        __builtin_amdgcn_s_setprio(0);

        // V B-fragments: bv[tl*2+dt][j] = V^T[dt*32+l32][ss*32+tl*16+hi*8+j]
        bf16x8 bv[4];
        #pragma unroll
        for (int tl = 0; tl < 2; ++tl)
            #pragma unroll
            for (int dt = 0; dt < 2; ++dt)
                bv[tl*2 + dt] = *(const bf16x8*)(
                    &VS[dt*32 + l32][((ss*4 + tl*2 + hi) ^ sw) * 8]);

        // softmax numerator, lane-local: p[r] = P[q=l32][crow(r,hi)]
        // raw v_exp_f32 (exact here: scores bounded, log2e pre-folded)
        float p[16];
        #pragma unroll
        for (int r = 0; r < 16; ++r) p[r] = __builtin_amdgcn_exp2f(sacc[r]);

        // pack to PV A-fragments: fr0 -> s_loc 0..15, fr1 -> s_loc 16..31
        union { uintx4 u; bf16x8 h; } fr0, fr1;
        {
            unsigned c0 = pk_bf16(p[0], p[1]);
            unsigned c1 = pk_bf16(p[2], p[3]);
            unsigned c2 = pk_bf16(p[4], p[5]);
            unsigned c3 = pk_bf16(p[6], p[7]);
            asm("v_permlane32_swap_b32 %0, %1" : "+v"(c0), "+v"(c2));
            asm("v_permlane32_swap_b32 %0, %1" : "+v"(c1), "+v"(c3));
            fr0.u = (uintx4){c0, c1, c2, c3};
        }
        {
            unsigned c0 = pk_bf16(p[8],  p[9]);
            unsigned c1 = pk_bf16(p[10], p[11]);
            unsigned c2 = pk_bf16(p[12], p[13]);
            unsigned c3 = pk_bf16(p[14], p[15]);
            asm("v_permlane32_swap_b32 %0, %1" : "+v"(c0), "+v"(c2));
            asm("v_permlane32_swap_b32 %0, %1" : "+v"(c1), "+v"(c3));
            fr1.u = (uintx4){c0, c1, c2, c3};
        }

        // denominator via ones-MFMA: oaccS row q = sum_s P[q][s] (all cols)
        __builtin_amdgcn_s_setprio(1);
        oaccS = __builtin_amdgcn_mfma_f32_32x32x16_bf16(fr0.h, ones, oaccS, 0, 0, 0);
        oaccS = __builtin_amdgcn_mfma_f32_32x32x16_bf16(fr1.h, ones, oaccS, 0, 0, 0);
        // PV: O[q][d] += P[q][s_loc] * V[s+s_loc][d]
        oacc0 = __builtin_amdgcn_mfma_f32_32x32x16_bf16(fr0.h, bv[0], oacc0, 0, 0, 0);
        oacc1 = __builtin_amdgcn_mfma_f32_32x32x16_bf16(fr0.h, bv[1], oacc1, 0, 0, 0);
        oacc0 = __builtin_amdgcn_mfma_f32_32x32x16_bf16(fr1.h, bv[2], oacc0, 0, 0, 0);
        oacc1 = __builtin_amdgcn_mfma_f32_32x32x16_bf16(fr1.h, bv[3], oacc1, 0, 0, 0);
        __builtin_amdgcn_s_setprio(0);
    }
}

__global__ __launch_bounds__(256, 3) void attn_mfma(
    const bf16* __restrict__ qf, const bf16* __restrict__ kf,
    const bf16* __restrict__ vf, bf16* __restrict__ Oa)
{
    __shared__ bf16 KsA[64][64], VtA[64][64];   // 16 KB (buffer A)
    __shared__ bf16 KsB[64][64], VtB[64][64];   // 16 KB (buffer B)

    const int bid = blockIdx.x;
    const int nh = bid % 48;                 // same head -> same XCD (bid%8 const)
    const int l0 = (bid / 48) * 128;
    const int tid  = threadIdx.x;
    const int wave = tid >> 6;
    const int lane = tid & 63;
    const int l32  = lane & 31;
    const int hi   = lane >> 5;
    const int sw   = l32 & 7;                // read-side swizzle

    const bf16* qb = qf + (size_t)nh * LL * HD;
    const bf16* kb = kf + (size_t)nh * LL * HD;
    const bf16* vb = vf + (size_t)nh * HD * LL;

    const int q0 = l0 + wave * 32;

    // staging geometry: 64 rows x 8 slots (16B) per tile; 2 chunks/thread
    const int rowA = tid >> 3;               // 0..31
    const int rowB = rowA + 32;              // 32..63
    const int g0   = tid & 7;                // logical slot
    const int gsA  = g0 ^ (rowA & 7);        // physical slot (rowB&7 == rowA&7)

    const bf16* pK0 = kb + (size_t)rowA*HD + g0*8;
    const bf16* pK1 = kb + (size_t)rowB*HD + g0*8;
    const bf16* pV0 = vb + (size_t)rowA*LL + g0*8;
    const bf16* pV1 = vb + (size_t)rowB*LL + g0*8;

    // Q B-fragments (col = q = l32, k-slice t): Q[q0+l32][t*16 + hi*8 + j]
    bf16x8 bq[4];
    #pragma unroll
    for (int t = 0; t < 4; ++t)
        bq[t] = *(const bf16x8*)(qb + (size_t)(q0 + l32)*HD + t*16 + hi*8);

    const bf16x8 ones = { (bf16)1.f, (bf16)1.f, (bf16)1.f, (bf16)1.f,
                          (bf16)1.f, (bf16)1.f, (bf16)1.f, (bf16)1.f };
    const floatx16 z16 = ZERO16;

    floatx16 oacc0 = ZERO16;   // O[q][d=l32]
    floatx16 oacc1 = ZERO16;   // O[q][d=32+l32]
    floatx16 oaccS = ZERO16;   // row sums (denominator)

    bf16x8 gk0, gk1, gv0, gv1;               // reg-staged tile

#define LOADT(S) do {                                                         \
        gk0 = *(const bf16x8*)(pK0 + (size_t)(S)*HD);                         \
        gk1 = *(const bf16x8*)(pK1 + (size_t)(S)*HD);                         \
        gv0 = *(const bf16x8*)(pV0 + (S));                                    \
        gv1 = *(const bf16x8*)(pV1 + (S));                                    \
    } while (0)
#define STORE_A() do {                                                        \
        *(bf16x8*)(&KsA[rowA][gsA*8]) = gk0;                                  \
        *(bf16x8*)(&KsA[rowB][gsA*8]) = gk1;                                  \
        *(bf16x8*)(&VtA[rowA][gsA*8]) = gv0;                                  \
        *(bf16x8*)(&VtA[rowB][gsA*8]) = gv1;                                  \
    } while (0)
#define STORE_B() do {                                                        \
        *(bf16x8*)(&KsB[rowA][gsA*8]) = gk0;                                  \
        *(bf16x8*)(&KsB[rowB][gsA*8]) = gk1;                                  \
        *(bf16x8*)(&VtB[rowA][gsA*8]) = gv0;                                  \
        *(bf16x8*)(&VtB[rowB][gsA*8]) = gv1;                                  \
    } while (0)

    LOADT(0);
    STORE_A();                               // tile 0 -> A
    LOADT(64);                               // tile 1 in regs
    __syncthreads();

    for (int tt = 0; tt < 16; ++tt) {
        STORE_B();                           // tile 2tt+1 -> B
        LOADT((size_t)((2*tt + 2) & 31) * 64);   // tile 2tt+2 (wraps at end)
        compute_tile(KsA, VtA, bq, ones, z16, l32, hi, sw, oacc0, oacc1, oaccS);
        __syncthreads();                     // B visible; all done reading A
        STORE_A();                           // tile 2tt+2 -> A
        LOADT((size_t)((2*tt + 3) & 31) * 64);   // tile 2tt+3 (wraps at end)
        compute_tile(KsB, VtB, bq, ones, z16, l32, hi, sw, oacc0, oacc1, oaccS);
        __syncthreads();                     // A visible; all done reading B
    }
#undef LOADT
#undef STORE_A
#undef STORE_B

    const int n = nh / HH, h = nh % HH;
    #pragma unroll
    for (int r = 0; r < 16; ++r) {
        const int qloc = (r & 3) + 8*(r >> 2) + 4*hi;
        const float iv = 1.f / oaccS[r];
        const size_t t = (size_t)(q0 + qloc)*NN + n;
        Oa[t*EE + h*64 + l32]      = (bf16)(oacc0[r] * iv);
        Oa[t*EE + h*64 + 32 + l32] = (bf16)(oacc1[r] * iv);
    }
}

// ---------------------------------------------------------------------------
extern "C" void kernel_launch(void* const* d_in, const int* in_sizes, int n_in,
                              void* d_out, int out_size, void* d_ws, size_t ws_size,
                              hipStream_t stream) {
    const float* q   = (const float*)d_in[0];
    const float* k   = (const float*)d_in[1];
    const float* v   = (const float*)d_in[2];
    const float* W   = (const float*)d_in[3];
    const float* b   = (const float*)d_in[4];
    const float* qd  = (const float*)d_in[5];
    const float* qu  = (const float*)d_in[6];
    const float* kd  = (const float*)d_in[7];
    const float* ku  = (const float*)d_in[8];
    const float* vd  = (const float*)d_in[9];
    const float* vu  = (const float*)d_in[10];
    const float* Wo  = (const float*)d_in[11];
    const float* bo  = (const float*)d_in[12];
    const float* odw = (const float*)d_in[13];
    const float* ou  = (const float*)d_in[14];
    float* out = (float*)d_out;

    char* wsb = (char*)d_ws;
    bf16* vfb = (bf16*)wsb;                       // [48][HD][LL]
    bf16* Oa  = (bf16*)(wsb + (size_t)TT*EE*2);   // [TT][EE]
    bf16* Wa  = (bf16*)(wsb + (size_t)3*TT*EE*2); // [3072][EE], 4.72 MB
    bf16* qfb = Wa + (size_t)3072*EE;
    bf16* kfb = qfb + (size_t)TT*EE;
    bf16* vld = kfb + (size_t)TT*EE;

    prep_w<<<192, 256, 0, stream>>>(W, qu, ku, vu, Wo, ou, qd, kd, vd, odw, Wa);
    gemm_aug<0><<<dim3(TT/128, F3/128), 256, 0, stream>>>(
        q, k, v, nullptr, Wa, b, qfb, kfb, vld, nullptr);
    vtrans<<<48*32, 256, 0, stream>>>(vld, vfb);
    attn_mfma<<<48*16, 256, 0, stream>>>(qfb, kfb, vfb, Oa);
    gemm_aug<1><<<dim3(TT/128, EE/128), 256, 0, stream>>>(
        nullptr, nullptr, nullptr, Oa, Wa + (size_t)F3*EE, bo,
        nullptr, nullptr, nullptr, out);
}